// Round 4
// baseline (842.512 us; speedup 1.0000x reference)
//
#include <hip/hip_runtime.h>
#include <hip/hip_bf16.h>

typedef __attribute__((ext_vector_type(8))) short short8;
typedef __attribute__((ext_vector_type(4))) float floatx4;
typedef __attribute__((ext_vector_type(4))) int int4v;
typedef __attribute__((ext_vector_type(4))) unsigned int uint4v;

#define MTBL 524288
#define HSTRIDE 72   // bf16 elements per point-row in LDS scratch (64+8 pad)

union U4S8 { uint4v u; short8 s; };

// fp32 -> bf16 round-to-nearest
static __device__ __forceinline__ unsigned int pack2bf(float a, float b) {
    union { float f; unsigned int u; } x, y;
    x.f = a; y.f = b;
    unsigned int lo = (x.u + 0x8000u) >> 16;
    unsigned int hi = (y.u + 0x8000u) & 0xFFFF0000u;
    return lo | hi;
}
static __device__ __forceinline__ short bf1(float a) {
    union { float f; unsigned int u; } x;
    x.f = a;
    return (short)((x.u + 0x8000u) >> 16);
}

// ---------------- Kernel T: compress tables fp32 [16*M][2] -> packed bf16 uint [16*M] ----
__global__ __launch_bounds__(256) void ngp_compress(
    const floatx4* __restrict__ tab4, unsigned int* __restrict__ tblC)
{
    const int t = blockIdx.x * 256 + threadIdx.x;   // handles entries 4t..4t+3
    floatx4 a = __builtin_nontemporal_load(tab4 + (size_t)2 * t);
    floatx4 b = __builtin_nontemporal_load(tab4 + (size_t)2 * t + 1);
    uint4v w;
    w[0] = pack2bf(a[0], a[1]);
    w[1] = pack2bf(a[2], a[3]);
    w[2] = pack2bf(b[0], b[1]);
    w[3] = pack2bf(b[2], b[3]);
    __builtin_nontemporal_store(w, (uint4v*)(tblC + (size_t)4 * t));
}

// ---------------- Kernel A: transpose idx [N][16] -> idxT [16][N] ----------------
__global__ __launch_bounds__(256) void ngp_transpose(
    const int* __restrict__ idx, int* __restrict__ idxT, int N)
{
    const int t  = blockIdx.x * 256 + threadIdx.x;   // handles points 4t..4t+3
    const int p0 = t * 4;
    const int4v* rows = (const int4v*)idx;
    int4v r[4][4];
#pragma unroll
    for (int p = 0; p < 4; ++p)
#pragma unroll
        for (int c = 0; c < 4; ++c)
            r[p][c] = __builtin_nontemporal_load(rows + (size_t)(p0 + p) * 4 + c);
#pragma unroll
    for (int c = 0; c < 4; ++c)
#pragma unroll
        for (int k = 0; k < 4; ++k) {
            const int h = c * 4 + k;
            int4v w;
            w[0] = r[0][c][k]; w[1] = r[1][c][k]; w[2] = r[2][c][k]; w[3] = r[3][c][k];
            __builtin_nontemporal_store(w, (int4v*)(idxT + (size_t)h * N + p0));
        }
}

// ---------------- Kernel B: one-head-per-XCD gather phase ----------------
// head = (blk&7)*2 + phase; per-XCD live table slice = 2 MiB (bf16-packed) < 4 MiB L2.
// idx reads / xU writes nontemporal; table gathers cached.
__global__ __launch_bounds__(256) void ngp_gather_ph(
    const int* __restrict__ idxT, const unsigned int* __restrict__ tblC,
    unsigned int* __restrict__ xU, int N, int phase, int iters)
{
    const int h    = ((blockIdx.x & 7) << 1) | phase;
    const int slot = blockIdx.x >> 3;                 // 0..255
    const int* __restrict__ ih = idxT + (size_t)h * N;
    const unsigned int* __restrict__ th = tblC + (size_t)h * MTBL;
    unsigned int* __restrict__ xh = xU + (size_t)h * N;

    int p = slot * (N >> 8) + (threadIdx.x << 3);     // 8 points per thread per iter
    int4v iv0 = __builtin_nontemporal_load((const int4v*)(ih + p));
    int4v iv1 = __builtin_nontemporal_load((const int4v*)(ih + p + 4));
    for (int it = 0; it < iters; ++it) {
        int4v nv0, nv1;
        if (it + 1 < iters) {
            nv0 = __builtin_nontemporal_load((const int4v*)(ih + p + 2048));
            nv1 = __builtin_nontemporal_load((const int4v*)(ih + p + 2052));
        }
        uint4v w0, w1;
        w0[0] = th[iv0[0]]; w0[1] = th[iv0[1]]; w0[2] = th[iv0[2]]; w0[3] = th[iv0[3]];
        w1[0] = th[iv1[0]]; w1[1] = th[iv1[1]]; w1[2] = th[iv1[2]]; w1[3] = th[iv1[3]];
        __builtin_nontemporal_store(w0, (uint4v*)(xh + p));
        __builtin_nontemporal_store(w1, (uint4v*)(xh + p + 4));
        iv0 = nv0; iv1 = nv1;
        p += 2048;
    }
}

// ---------------- Kernel C: MFMA MLP on contiguous xU ----------------
__global__ __launch_bounds__(256, 4) void ngp_mlp(
    const unsigned int* __restrict__ xU,
    const float* __restrict__ W1, const float* __restrict__ b1,
    const float* __restrict__ W2, const float* __restrict__ b2,
    const float* __restrict__ W3, const float* __restrict__ b3,
    const float* __restrict__ W4, const float* __restrict__ b4,
    float* __restrict__ out, int N, int tiles_per_wave)
{
    __shared__ float sW[6144];                        // 24 KB, reused across 2 stages
    __shared__ __hip_bfloat16 sH[4][16 * HSTRIDE];    // 9.2 KB wave-private scratch

    const int tid  = threadIdx.x;
    const int wave = tid >> 6;
    const int lane = tid & 63;
    const int q = lane >> 4;
    const int m = lane & 15;

    short8 A1[4], A2[4][2], A3[4][2], A4[2];
    floatx4 C1[4], C2[4], C3[4], C4;

    // ---- stage A: W1 (2048) + W2 (4096) ----
    for (int i = tid; i < 2048; i += 256) sW[i] = W1[i];
    for (int i = tid; i < 4096; i += 256) sW[2048 + i] = W2[i];
    __syncthreads();
#pragma unroll
    for (int t = 0; t < 4; ++t) {
        short8 a;
#pragma unroll
        for (int j = 0; j < 8; ++j)
            a[j] = bf1(sW[(q * 8 + j) * 64 + t * 16 + m]);
        A1[t] = a;
    }
#pragma unroll
    for (int t = 0; t < 4; ++t)
#pragma unroll
        for (int c = 0; c < 2; ++c) {
            short8 a;
#pragma unroll
            for (int j = 0; j < 8; ++j)
                a[j] = bf1(sW[2048 + (c * 32 + q * 8 + j) * 64 + t * 16 + m]);
            A2[t][c] = a;
        }
    __syncthreads();

    // ---- stage B: W3 (4096) + W4 (192) + biases (195) ----
    for (int i = tid; i < 4096; i += 256) sW[i] = W3[i];
    if (tid < 192) sW[4096 + tid] = W4[tid];
    if (tid < 64)       sW[4288 + tid] = b1[tid];
    else if (tid < 128) sW[4288 + tid] = b2[tid - 64];
    else if (tid < 192) sW[4288 + tid] = b3[tid - 128];
    else if (tid < 195) sW[4288 + tid] = b4[tid - 192];
    __syncthreads();
#pragma unroll
    for (int t = 0; t < 4; ++t)
#pragma unroll
        for (int c = 0; c < 2; ++c) {
            short8 a;
#pragma unroll
            for (int j = 0; j < 8; ++j)
                a[j] = bf1(sW[(c * 32 + q * 8 + j) * 64 + t * 16 + m]);
            A3[t][c] = a;
        }
#pragma unroll
    for (int c = 0; c < 2; ++c) {
        short8 a;
#pragma unroll
        for (int j = 0; j < 8; ++j)
            a[j] = (m < 3) ? bf1(sW[4096 + (c * 32 + q * 8 + j) * 3 + m]) : (short)0;
        A4[c] = a;
    }
#pragma unroll
    for (int t = 0; t < 4; ++t)
#pragma unroll
        for (int r = 0; r < 4; ++r) {
            C1[t][r] = sW[4288 + t * 16 + q * 4 + r];
            C2[t][r] = sW[4288 + 64 + t * 16 + q * 4 + r];
            C3[t][r] = sW[4288 + 128 + t * 16 + q * 4 + r];
        }
#pragma unroll
    for (int r = 0; r < 4; ++r)
        C4[r] = (q == 0 && r < 3) ? sW[4288 + 192 + r] : 0.0f;

    __hip_bfloat16* hrow = &sH[wave][m * HSTRIDE];
    const int gw = blockIdx.x * 4 + wave;
    const int tile0 = gw * tiles_per_wave;

    const unsigned int* xr = xU + (size_t)(q * 4) * N + m;

    uint4v cur;
    {
        const int c0 = tile0 * 16;
        cur[0] = xr[c0];
        cur[1] = xr[(size_t)N + c0];
        cur[2] = xr[(size_t)2 * N + c0];
        cur[3] = xr[(size_t)3 * N + c0];
    }

    for (int it = 0; it < tiles_per_wave; ++it) {
        const int pbase = (tile0 + it) * 16;
        const bool more = (it + 1) < tiles_per_wave;

        U4S8 bx; bx.u = cur;
        const short8 Bx = bx.s;

        uint4v nxt;
        if (more) {
            const int cn = pbase + 16;
            nxt[0] = xr[cn];
            nxt[1] = xr[(size_t)N + cn];
            nxt[2] = xr[(size_t)2 * N + cn];
            nxt[3] = xr[(size_t)3 * N + cn];
        }

        // ---- layer 1 ----
        floatx4 acc[4];
#pragma unroll
        for (int t = 0; t < 4; ++t)
            acc[t] = __builtin_amdgcn_mfma_f32_16x16x32_bf16(A1[t], Bx, C1[t], 0, 0, 0);

#pragma unroll
        for (int t = 0; t < 4; ++t) {
            uint2 pk;
            pk.x = pack2bf(fmaxf(acc[t][0], 0.f), fmaxf(acc[t][1], 0.f));
            pk.y = pack2bf(fmaxf(acc[t][2], 0.f), fmaxf(acc[t][3], 0.f));
            *(uint2*)(hrow + t * 16 + q * 4) = pk;
        }
        short8 Bh0 = *(const short8*)(hrow + q * 8);
        short8 Bh1 = *(const short8*)(hrow + 32 + q * 8);

        // ---- layer 2 ----
#pragma unroll
        for (int t = 0; t < 4; ++t) {
            acc[t] = __builtin_amdgcn_mfma_f32_16x16x32_bf16(A2[t][0], Bh0, C2[t], 0, 0, 0);
            acc[t] = __builtin_amdgcn_mfma_f32_16x16x32_bf16(A2[t][1], Bh1, acc[t], 0, 0, 0);
        }

#pragma unroll
        for (int t = 0; t < 4; ++t) {
            uint2 pk;
            pk.x = pack2bf(fmaxf(acc[t][0], 0.f), fmaxf(acc[t][1], 0.f));
            pk.y = pack2bf(fmaxf(acc[t][2], 0.f), fmaxf(acc[t][3], 0.f));
            *(uint2*)(hrow + t * 16 + q * 4) = pk;
        }
        Bh0 = *(const short8*)(hrow + q * 8);
        Bh1 = *(const short8*)(hrow + 32 + q * 8);

        // ---- layer 3 ----
#pragma unroll
        for (int t = 0; t < 4; ++t) {
            acc[t] = __builtin_amdgcn_mfma_f32_16x16x32_bf16(A3[t][0], Bh0, C3[t], 0, 0, 0);
            acc[t] = __builtin_amdgcn_mfma_f32_16x16x32_bf16(A3[t][1], Bh1, acc[t], 0, 0, 0);
        }

#pragma unroll
        for (int t = 0; t < 4; ++t) {
            uint2 pk;
            pk.x = pack2bf(fmaxf(acc[t][0], 0.f), fmaxf(acc[t][1], 0.f));
            pk.y = pack2bf(fmaxf(acc[t][2], 0.f), fmaxf(acc[t][3], 0.f));
            *(uint2*)(hrow + t * 16 + q * 4) = pk;
        }
        Bh0 = *(const short8*)(hrow + q * 8);
        Bh1 = *(const short8*)(hrow + 32 + q * 8);

        // ---- layer 4 ----
        floatx4 o;
        o = __builtin_amdgcn_mfma_f32_16x16x32_bf16(A4[0], Bh0, C4, 0, 0, 0);
        o = __builtin_amdgcn_mfma_f32_16x16x32_bf16(A4[1], Bh1, o, 0, 0, 0);

        if (q == 0) {
            const int pn = pbase + m;
            out[pn * 3 + 0] = o[0];
            out[pn * 3 + 1] = o[1];
            out[pn * 3 + 2] = o[2];
        }

        cur = nxt;
    }
}

// ---------------- Fallback: R1 fused kernel (ws too small) ----------------
__global__ __launch_bounds__(256, 2) void ngp_fused(
    const int* __restrict__ idx,
    const float* __restrict__ tables,
    const float* __restrict__ W1, const float* __restrict__ b1,
    const float* __restrict__ W2, const float* __restrict__ b2,
    const float* __restrict__ W3, const float* __restrict__ b3,
    const float* __restrict__ W4, const float* __restrict__ b4,
    float* __restrict__ out, int tiles_per_wave)
{
    __shared__ float sW1[2048];
    __shared__ float sW2[4096];
    __shared__ float sW3[4096];
    __shared__ float sW4[192];
    __shared__ float sB[200];
    __shared__ __hip_bfloat16 sH[4][16 * HSTRIDE];

    const int tid = threadIdx.x;
    for (int i = tid; i < 2048; i += 256) sW1[i] = W1[i];
    for (int i = tid; i < 4096; i += 256) sW2[i] = W2[i];
    for (int i = tid; i < 4096; i += 256) sW3[i] = W3[i];
    if (tid < 192) sW4[tid] = W4[tid];
    if (tid < 64)       sB[tid] = b1[tid];
    else if (tid < 128) sB[tid] = b2[tid - 64];
    else if (tid < 192) sB[tid] = b3[tid - 128];
    else if (tid < 195) sB[tid] = b4[tid - 192];
    __syncthreads();

    const int wave = tid >> 6;
    const int lane = tid & 63;
    const int q = lane >> 4;
    const int m = lane & 15;

    short8 A1[4], A2[4][2], A3[4][2], A4[2];
#pragma unroll
    for (int t = 0; t < 4; ++t) {
        short8 a;
#pragma unroll
        for (int j = 0; j < 8; ++j)
            a[j] = bf1(sW1[(q * 8 + j) * 64 + t * 16 + m]);
        A1[t] = a;
    }
#pragma unroll
    for (int t = 0; t < 4; ++t)
#pragma unroll
        for (int c = 0; c < 2; ++c) {
            short8 a, a3;
#pragma unroll
            for (int j = 0; j < 8; ++j) {
                a[j]  = bf1(sW2[(c * 32 + q * 8 + j) * 64 + t * 16 + m]);
                a3[j] = bf1(sW3[(c * 32 + q * 8 + j) * 64 + t * 16 + m]);
            }
            A2[t][c] = a;
            A3[t][c] = a3;
        }
#pragma unroll
    for (int c = 0; c < 2; ++c) {
        short8 a;
#pragma unroll
        for (int j = 0; j < 8; ++j)
            a[j] = (m < 3) ? bf1(sW4[(c * 32 + q * 8 + j) * 3 + m]) : (short)0;
        A4[c] = a;
    }

    floatx4 C1[4], C2[4], C3[4], C4;
#pragma unroll
    for (int t = 0; t < 4; ++t)
#pragma unroll
        for (int r = 0; r < 4; ++r) {
            C1[t][r] = sB[t * 16 + q * 4 + r];
            C2[t][r] = sB[64 + t * 16 + q * 4 + r];
            C3[t][r] = sB[128 + t * 16 + q * 4 + r];
        }
#pragma unroll
    for (int r = 0; r < 4; ++r)
        C4[r] = (q == 0 && r < 3) ? sB[192 + r] : 0.0f;

    __hip_bfloat16* hrow = &sH[wave][m * HSTRIDE];
    const int4*   idx4 = (const int4*)idx;
    const float2* tbl  = (const float2*)tables;

    const int gw = blockIdx.x * 4 + wave;
    const int tile0 = gw * tiles_per_wave;

    int4 iv = idx4[(tile0 * 16 + m) * 4 + q];
    float2 g0 = tbl[(q * 4 + 0) * MTBL + iv.x];
    float2 g1 = tbl[(q * 4 + 1) * MTBL + iv.y];
    float2 g2 = tbl[(q * 4 + 2) * MTBL + iv.z];
    float2 g3 = tbl[(q * 4 + 3) * MTBL + iv.w];

    for (int it = 0; it < tiles_per_wave; ++it) {
        const int pbase = (tile0 + it) * 16;
        const bool more = (it + 1) < tiles_per_wave;

        short8 Bx;
        {
            unsigned int p0 = pack2bf(g0.x, g0.y);
            unsigned int p1 = pack2bf(g1.x, g1.y);
            unsigned int p2 = pack2bf(g2.x, g2.y);
            unsigned int p3 = pack2bf(g3.x, g3.y);
            Bx[0] = (short)(p0 & 0xFFFF); Bx[1] = (short)(p0 >> 16);
            Bx[2] = (short)(p1 & 0xFFFF); Bx[3] = (short)(p1 >> 16);
            Bx[4] = (short)(p2 & 0xFFFF); Bx[5] = (short)(p2 >> 16);
            Bx[6] = (short)(p3 & 0xFFFF); Bx[7] = (short)(p3 >> 16);
        }

        int4 ivn;
        if (more) ivn = idx4[((pbase + 16) + m) * 4 + q];

        floatx4 acc[4];
#pragma unroll
        for (int t = 0; t < 4; ++t)
            acc[t] = __builtin_amdgcn_mfma_f32_16x16x32_bf16(A1[t], Bx, C1[t], 0, 0, 0);

#pragma unroll
        for (int t = 0; t < 4; ++t) {
            uint2 pk;
            pk.x = pack2bf(fmaxf(acc[t][0], 0.f), fmaxf(acc[t][1], 0.f));
            pk.y = pack2bf(fmaxf(acc[t][2], 0.f), fmaxf(acc[t][3], 0.f));
            *(uint2*)(hrow + t * 16 + q * 4) = pk;
        }
        short8 Bh0 = *(const short8*)(hrow + q * 8);
        short8 Bh1 = *(const short8*)(hrow + 32 + q * 8);

#pragma unroll
        for (int t = 0; t < 4; ++t) {
            acc[t] = __builtin_amdgcn_mfma_f32_16x16x32_bf16(A2[t][0], Bh0, C2[t], 0, 0, 0);
            acc[t] = __builtin_amdgcn_mfma_f32_16x16x32_bf16(A2[t][1], Bh1, acc[t], 0, 0, 0);
        }

        if (more) {
            g0 = tbl[(q * 4 + 0) * MTBL + ivn.x];
            g1 = tbl[(q * 4 + 1) * MTBL + ivn.y];
            g2 = tbl[(q * 4 + 2) * MTBL + ivn.z];
            g3 = tbl[(q * 4 + 3) * MTBL + ivn.w];
        }

#pragma unroll
        for (int t = 0; t < 4; ++t) {
            uint2 pk;
            pk.x = pack2bf(fmaxf(acc[t][0], 0.f), fmaxf(acc[t][1], 0.f));
            pk.y = pack2bf(fmaxf(acc[t][2], 0.f), fmaxf(acc[t][3], 0.f));
            *(uint2*)(hrow + t * 16 + q * 4) = pk;
        }
        Bh0 = *(const short8*)(hrow + q * 8);
        Bh1 = *(const short8*)(hrow + 32 + q * 8);

#pragma unroll
        for (int t = 0; t < 4; ++t) {
            acc[t] = __builtin_amdgcn_mfma_f32_16x16x32_bf16(A3[t][0], Bh0, C3[t], 0, 0, 0);
            acc[t] = __builtin_amdgcn_mfma_f32_16x16x32_bf16(A3[t][1], Bh1, acc[t], 0, 0, 0);
        }

#pragma unroll
        for (int t = 0; t < 4; ++t) {
            uint2 pk;
            pk.x = pack2bf(fmaxf(acc[t][0], 0.f), fmaxf(acc[t][1], 0.f));
            pk.y = pack2bf(fmaxf(acc[t][2], 0.f), fmaxf(acc[t][3], 0.f));
            *(uint2*)(hrow + t * 16 + q * 4) = pk;
        }
        Bh0 = *(const short8*)(hrow + q * 8);
        Bh1 = *(const short8*)(hrow + 32 + q * 8);

        floatx4 o;
        o = __builtin_amdgcn_mfma_f32_16x16x32_bf16(A4[0], Bh0, C4, 0, 0, 0);
        o = __builtin_amdgcn_mfma_f32_16x16x32_bf16(A4[1], Bh1, o, 0, 0, 0);

        if (q == 0) {
            const int pn = pbase + m;
            out[pn * 3 + 0] = o[0];
            out[pn * 3 + 1] = o[1];
            out[pn * 3 + 2] = o[2];
        }
    }
}

extern "C" void kernel_launch(void* const* d_in, const int* in_sizes, int n_in,
                              void* d_out, int out_size, void* d_ws, size_t ws_size,
                              hipStream_t stream) {
    const int*   idx    = (const int*)d_in[0];
    const float* tables = (const float*)d_in[1];
    const float* W1 = (const float*)d_in[2];
    const float* b1 = (const float*)d_in[3];
    const float* W2 = (const float*)d_in[4];
    const float* b2 = (const float*)d_in[5];
    const float* W3 = (const float*)d_in[6];
    const float* b3 = (const float*)d_in[7];
    const float* W4 = (const float*)d_in[8];
    const float* b4 = (const float*)d_in[9];
    float* out = (float*)d_out;

    const int N = in_sizes[0] / 16;            // points (2,097,152)
    const int total_tiles = N / 16;

    const size_t idxT_bytes = (size_t)16 * N * 4;           // 128 MiB
    const size_t xU_bytes   = (size_t)16 * N * 4;           // 128 MiB
    const size_t tblC_bytes = (size_t)16 * MTBL * 4;        // 32 MiB
    const size_t need = idxT_bytes + xU_bytes + tblC_bytes;

    if (ws_size >= need) {
        int*          idxT = (int*)d_ws;
        unsigned int* xU   = (unsigned int*)((char*)d_ws + idxT_bytes);
        unsigned int* tblC = (unsigned int*)((char*)d_ws + idxT_bytes + xU_bytes);

        // A: transpose idx
        ngp_transpose<<<N / 1024, 256, 0, stream>>>(idx, idxT, N);
        // T: compress tables to packed bf16 (16*M entries, 4 per thread)
        ngp_compress<<<(16 * MTBL) / 1024, 256, 0, stream>>>(
            (const floatx4*)tables, tblC);
        // B: two gather phases, one head per XCD each
        const int iters = (N >> 8) >> 11;   // points/block / 2048
        ngp_gather_ph<<<2048, 256, 0, stream>>>(idxT, tblC, xU, N, 0, iters);
        ngp_gather_ph<<<2048, 256, 0, stream>>>(idxT, tblC, xU, N, 1, iters);
        // C: MFMA MLP
        const int blocks = 2048;
        const int tiles_per_wave = total_tiles / (blocks * 4);
        ngp_mlp<<<blocks, 256, 0, stream>>>(xU, W1, b1, W2, b2, W3, b3, W4, b4,
                                            out, N, tiles_per_wave);
    } else {
        const int blocks = 2048;
        const int tiles_per_wave = total_tiles / (blocks * 4);
        ngp_fused<<<blocks, 256, 0, stream>>>(idx, tables, W1, b1, W2, b2, W3, b3,
                                              W4, b4, out, tiles_per_wave);
    }
}

// Round 5
// 649.909 us; speedup vs baseline: 1.2964x; 1.2964x over previous
//
#include <hip/hip_runtime.h>
#include <hip/hip_bf16.h>

typedef __attribute__((ext_vector_type(8))) short short8;
typedef __attribute__((ext_vector_type(4))) float floatx4;
typedef __attribute__((ext_vector_type(4))) int int4v;
typedef __attribute__((ext_vector_type(4))) unsigned int uint4v;

#define MTBL 524288
#define HSTRIDE 72   // bf16 elements per point-row in LDS scratch (64+8 pad)

union U4S8 { uint4v u; short8 s; };

// fp32 -> bf16 round-to-nearest
static __device__ __forceinline__ unsigned int pack2bf(float a, float b) {
    union { float f; unsigned int u; } x, y;
    x.f = a; y.f = b;
    unsigned int lo = (x.u + 0x8000u) >> 16;
    unsigned int hi = (y.u + 0x8000u) & 0xFFFF0000u;
    return lo | hi;
}
static __device__ __forceinline__ short bf1(float a) {
    union { float f; unsigned int u; } x;
    x.f = a;
    return (short)((x.u + 0x8000u) >> 16);
}

// ---------------- Kernel T: compress tables fp32 [16*M][2] -> packed bf16 uint [16*M] ----
__global__ __launch_bounds__(256) void ngp_compress(
    const floatx4* __restrict__ tab4, unsigned int* __restrict__ tblC)
{
    const int t = blockIdx.x * 256 + threadIdx.x;   // handles entries 4t..4t+3
    floatx4 a = __builtin_nontemporal_load(tab4 + (size_t)2 * t);
    floatx4 b = __builtin_nontemporal_load(tab4 + (size_t)2 * t + 1);
    uint4v w;
    w[0] = pack2bf(a[0], a[1]);
    w[1] = pack2bf(a[2], a[3]);
    w[2] = pack2bf(b[0], b[1]);
    w[3] = pack2bf(b[2], b[3]);
    __builtin_nontemporal_store(w, (uint4v*)(tblC + (size_t)4 * t));
}

// ---------------- Kernel A: transpose idx [N][16] -> idxT [16][N] ----------------
__global__ __launch_bounds__(256) void ngp_transpose(
    const int* __restrict__ idx, int* __restrict__ idxT, int N)
{
    const int t  = blockIdx.x * 256 + threadIdx.x;   // handles points 4t..4t+3
    const int p0 = t * 4;
    const int4v* rows = (const int4v*)idx;
    int4v r[4][4];
#pragma unroll
    for (int p = 0; p < 4; ++p)
#pragma unroll
        for (int c = 0; c < 4; ++c)
            r[p][c] = __builtin_nontemporal_load(rows + (size_t)(p0 + p) * 4 + c);
#pragma unroll
    for (int c = 0; c < 4; ++c)
#pragma unroll
        for (int k = 0; k < 4; ++k) {
            const int h = c * 4 + k;
            int4v w;
            w[0] = r[0][c][k]; w[1] = r[1][c][k]; w[2] = r[2][c][k]; w[3] = r[3][c][k];
            __builtin_nontemporal_store(w, (int4v*)(idxT + (size_t)h * N + p0));
        }
}

// ---------------- Kernel B: one-head-per-XCD gather phase ----------------
// head = (blk&7)*2 + phase; per-XCD live table slice = 2 MiB (bf16-packed) < 4 MiB L2.
// idx reads / xU writes nontemporal; table gathers cached.
__global__ __launch_bounds__(256) void ngp_gather_ph(
    const int* __restrict__ idxT, const unsigned int* __restrict__ tblC,
    unsigned int* __restrict__ xU, int N, int phase, int iters)
{
    const int h    = ((blockIdx.x & 7) << 1) | phase;
    const int slot = blockIdx.x >> 3;                 // 0..255
    const int* __restrict__ ih = idxT + (size_t)h * N;
    const unsigned int* __restrict__ th = tblC + (size_t)h * MTBL;
    unsigned int* __restrict__ xh = xU + (size_t)h * N;

    int p = slot * (N >> 8) + (threadIdx.x << 3);     // 8 points per thread per iter
    int4v iv0 = __builtin_nontemporal_load((const int4v*)(ih + p));
    int4v iv1 = __builtin_nontemporal_load((const int4v*)(ih + p + 4));
    for (int it = 0; it < iters; ++it) {
        int4v nv0, nv1;
        if (it + 1 < iters) {
            nv0 = __builtin_nontemporal_load((const int4v*)(ih + p + 2048));
            nv1 = __builtin_nontemporal_load((const int4v*)(ih + p + 2052));
        }
        uint4v w0, w1;
        w0[0] = th[iv0[0]]; w0[1] = th[iv0[1]]; w0[2] = th[iv0[2]]; w0[3] = th[iv0[3]];
        w1[0] = th[iv1[0]]; w1[1] = th[iv1[1]]; w1[2] = th[iv1[2]]; w1[3] = th[iv1[3]];
        __builtin_nontemporal_store(w0, (uint4v*)(xh + p));
        __builtin_nontemporal_store(w1, (uint4v*)(xh + p + 4));
        iv0 = nv0; iv1 = nv1;
        p += 2048;
    }
}

// ---------------- Kernel C: MFMA MLP on contiguous xU ----------------
// launch_bounds (256,2): allows ~180 VGPRs -> the ~130 live regs fit, NO SPILL.
// (256,4) forced VGPR=64 and spilled the resident weight fragments: mlp FETCH
// ballooned 140 MB -> 970 MB and the kernel ran 361 us pure-spill-bound (R4).
__global__ __launch_bounds__(256, 2) void ngp_mlp(
    const unsigned int* __restrict__ xU,
    const float* __restrict__ W1, const float* __restrict__ b1,
    const float* __restrict__ W2, const float* __restrict__ b2,
    const float* __restrict__ W3, const float* __restrict__ b3,
    const float* __restrict__ W4, const float* __restrict__ b4,
    float* __restrict__ out, int N, int tiles_per_wave)
{
    __shared__ float sW[6144];                        // 24 KB, reused across 2 stages
    __shared__ __hip_bfloat16 sH[4][16 * HSTRIDE];    // 9.2 KB wave-private scratch

    const int tid  = threadIdx.x;
    const int wave = tid >> 6;
    const int lane = tid & 63;
    const int q = lane >> 4;
    const int m = lane & 15;

    short8 A1[4], A2[4][2], A3[4][2], A4[2];
    floatx4 C1[4], C2[4], C3[4], C4;

    // ---- stage A: W1 (2048) + W2 (4096) ----
    for (int i = tid; i < 2048; i += 256) sW[i] = W1[i];
    for (int i = tid; i < 4096; i += 256) sW[2048 + i] = W2[i];
    __syncthreads();
#pragma unroll
    for (int t = 0; t < 4; ++t) {
        short8 a;
#pragma unroll
        for (int j = 0; j < 8; ++j)
            a[j] = bf1(sW[(q * 8 + j) * 64 + t * 16 + m]);
        A1[t] = a;
    }
#pragma unroll
    for (int t = 0; t < 4; ++t)
#pragma unroll
        for (int c = 0; c < 2; ++c) {
            short8 a;
#pragma unroll
            for (int j = 0; j < 8; ++j)
                a[j] = bf1(sW[2048 + (c * 32 + q * 8 + j) * 64 + t * 16 + m]);
            A2[t][c] = a;
        }
    __syncthreads();

    // ---- stage B: W3 (4096) + W4 (192) + biases (195) ----
    for (int i = tid; i < 4096; i += 256) sW[i] = W3[i];
    if (tid < 192) sW[4096 + tid] = W4[tid];
    if (tid < 64)       sW[4288 + tid] = b1[tid];
    else if (tid < 128) sW[4288 + tid] = b2[tid - 64];
    else if (tid < 192) sW[4288 + tid] = b3[tid - 128];
    else if (tid < 195) sW[4288 + tid] = b4[tid - 192];
    __syncthreads();
#pragma unroll
    for (int t = 0; t < 4; ++t)
#pragma unroll
        for (int c = 0; c < 2; ++c) {
            short8 a;
#pragma unroll
            for (int j = 0; j < 8; ++j)
                a[j] = bf1(sW[(c * 32 + q * 8 + j) * 64 + t * 16 + m]);
            A3[t][c] = a;
        }
#pragma unroll
    for (int c = 0; c < 2; ++c) {
        short8 a;
#pragma unroll
        for (int j = 0; j < 8; ++j)
            a[j] = (m < 3) ? bf1(sW[4096 + (c * 32 + q * 8 + j) * 3 + m]) : (short)0;
        A4[c] = a;
    }
#pragma unroll
    for (int t = 0; t < 4; ++t)
#pragma unroll
        for (int r = 0; r < 4; ++r) {
            C1[t][r] = sW[4288 + t * 16 + q * 4 + r];
            C2[t][r] = sW[4288 + 64 + t * 16 + q * 4 + r];
            C3[t][r] = sW[4288 + 128 + t * 16 + q * 4 + r];
        }
#pragma unroll
    for (int r = 0; r < 4; ++r)
        C4[r] = (q == 0 && r < 3) ? sW[4288 + 192 + r] : 0.0f;

    __hip_bfloat16* hrow = &sH[wave][m * HSTRIDE];
    const int gw = blockIdx.x * 4 + wave;
    const int tile0 = gw * tiles_per_wave;

    const unsigned int* xr = xU + (size_t)(q * 4) * N + m;

    uint4v cur;
    {
        const int c0 = tile0 * 16;
        cur[0] = xr[c0];
        cur[1] = xr[(size_t)N + c0];
        cur[2] = xr[(size_t)2 * N + c0];
        cur[3] = xr[(size_t)3 * N + c0];
    }

    for (int it = 0; it < tiles_per_wave; ++it) {
        const int pbase = (tile0 + it) * 16;
        const bool more = (it + 1) < tiles_per_wave;

        U4S8 bx; bx.u = cur;
        const short8 Bx = bx.s;

        uint4v nxt;
        if (more) {
            const int cn = pbase + 16;
            nxt[0] = xr[cn];
            nxt[1] = xr[(size_t)N + cn];
            nxt[2] = xr[(size_t)2 * N + cn];
            nxt[3] = xr[(size_t)3 * N + cn];
        }

        // ---- layer 1 ----
        floatx4 acc[4];
#pragma unroll
        for (int t = 0; t < 4; ++t)
            acc[t] = __builtin_amdgcn_mfma_f32_16x16x32_bf16(A1[t], Bx, C1[t], 0, 0, 0);

#pragma unroll
        for (int t = 0; t < 4; ++t) {
            uint2 pk;
            pk.x = pack2bf(fmaxf(acc[t][0], 0.f), fmaxf(acc[t][1], 0.f));
            pk.y = pack2bf(fmaxf(acc[t][2], 0.f), fmaxf(acc[t][3], 0.f));
            *(uint2*)(hrow + t * 16 + q * 4) = pk;
        }
        short8 Bh0 = *(const short8*)(hrow + q * 8);
        short8 Bh1 = *(const short8*)(hrow + 32 + q * 8);

        // ---- layer 2 ----
#pragma unroll
        for (int t = 0; t < 4; ++t) {
            acc[t] = __builtin_amdgcn_mfma_f32_16x16x32_bf16(A2[t][0], Bh0, C2[t], 0, 0, 0);
            acc[t] = __builtin_amdgcn_mfma_f32_16x16x32_bf16(A2[t][1], Bh1, acc[t], 0, 0, 0);
        }

#pragma unroll
        for (int t = 0; t < 4; ++t) {
            uint2 pk;
            pk.x = pack2bf(fmaxf(acc[t][0], 0.f), fmaxf(acc[t][1], 0.f));
            pk.y = pack2bf(fmaxf(acc[t][2], 0.f), fmaxf(acc[t][3], 0.f));
            *(uint2*)(hrow + t * 16 + q * 4) = pk;
        }
        Bh0 = *(const short8*)(hrow + q * 8);
        Bh1 = *(const short8*)(hrow + 32 + q * 8);

        // ---- layer 3 ----
#pragma unroll
        for (int t = 0; t < 4; ++t) {
            acc[t] = __builtin_amdgcn_mfma_f32_16x16x32_bf16(A3[t][0], Bh0, C3[t], 0, 0, 0);
            acc[t] = __builtin_amdgcn_mfma_f32_16x16x32_bf16(A3[t][1], Bh1, acc[t], 0, 0, 0);
        }

#pragma unroll
        for (int t = 0; t < 4; ++t) {
            uint2 pk;
            pk.x = pack2bf(fmaxf(acc[t][0], 0.f), fmaxf(acc[t][1], 0.f));
            pk.y = pack2bf(fmaxf(acc[t][2], 0.f), fmaxf(acc[t][3], 0.f));
            *(uint2*)(hrow + t * 16 + q * 4) = pk;
        }
        Bh0 = *(const short8*)(hrow + q * 8);
        Bh1 = *(const short8*)(hrow + 32 + q * 8);

        // ---- layer 4 ----
        floatx4 o;
        o = __builtin_amdgcn_mfma_f32_16x16x32_bf16(A4[0], Bh0, C4, 0, 0, 0);
        o = __builtin_amdgcn_mfma_f32_16x16x32_bf16(A4[1], Bh1, o, 0, 0, 0);

        if (q == 0) {
            const int pn = pbase + m;
            out[pn * 3 + 0] = o[0];
            out[pn * 3 + 1] = o[1];
            out[pn * 3 + 2] = o[2];
        }

        cur = nxt;
    }
}

// ---------------- Fallback: R1 fused kernel (ws too small) ----------------
__global__ __launch_bounds__(256, 2) void ngp_fused(
    const int* __restrict__ idx,
    const float* __restrict__ tables,
    const float* __restrict__ W1, const float* __restrict__ b1,
    const float* __restrict__ W2, const float* __restrict__ b2,
    const float* __restrict__ W3, const float* __restrict__ b3,
    const float* __restrict__ W4, const float* __restrict__ b4,
    float* __restrict__ out, int tiles_per_wave)
{
    __shared__ float sW1[2048];
    __shared__ float sW2[4096];
    __shared__ float sW3[4096];
    __shared__ float sW4[192];
    __shared__ float sB[200];
    __shared__ __hip_bfloat16 sH[4][16 * HSTRIDE];

    const int tid = threadIdx.x;
    for (int i = tid; i < 2048; i += 256) sW1[i] = W1[i];
    for (int i = tid; i < 4096; i += 256) sW2[i] = W2[i];
    for (int i = tid; i < 4096; i += 256) sW3[i] = W3[i];
    if (tid < 192) sW4[tid] = W4[tid];
    if (tid < 64)       sB[tid] = b1[tid];
    else if (tid < 128) sB[tid] = b2[tid - 64];
    else if (tid < 192) sB[tid] = b3[tid - 128];
    else if (tid < 195) sB[tid] = b4[tid - 192];
    __syncthreads();

    const int wave = tid >> 6;
    const int lane = tid & 63;
    const int q = lane >> 4;
    const int m = lane & 15;

    short8 A1[4], A2[4][2], A3[4][2], A4[2];
#pragma unroll
    for (int t = 0; t < 4; ++t) {
        short8 a;
#pragma unroll
        for (int j = 0; j < 8; ++j)
            a[j] = bf1(sW1[(q * 8 + j) * 64 + t * 16 + m]);
        A1[t] = a;
    }
#pragma unroll
    for (int t = 0; t < 4; ++t)
#pragma unroll
        for (int c = 0; c < 2; ++c) {
            short8 a, a3;
#pragma unroll
            for (int j = 0; j < 8; ++j) {
                a[j]  = bf1(sW2[(c * 32 + q * 8 + j) * 64 + t * 16 + m]);
                a3[j] = bf1(sW3[(c * 32 + q * 8 + j) * 64 + t * 16 + m]);
            }
            A2[t][c] = a;
            A3[t][c] = a3;
        }
#pragma unroll
    for (int c = 0; c < 2; ++c) {
        short8 a;
#pragma unroll
        for (int j = 0; j < 8; ++j)
            a[j] = (m < 3) ? bf1(sW4[(c * 32 + q * 8 + j) * 3 + m]) : (short)0;
        A4[c] = a;
    }

    floatx4 C1[4], C2[4], C3[4], C4;
#pragma unroll
    for (int t = 0; t < 4; ++t)
#pragma unroll
        for (int r = 0; r < 4; ++r) {
            C1[t][r] = sB[t * 16 + q * 4 + r];
            C2[t][r] = sB[64 + t * 16 + q * 4 + r];
            C3[t][r] = sB[128 + t * 16 + q * 4 + r];
        }
#pragma unroll
    for (int r = 0; r < 4; ++r)
        C4[r] = (q == 0 && r < 3) ? sB[192 + r] : 0.0f;

    __hip_bfloat16* hrow = &sH[wave][m * HSTRIDE];
    const int4*   idx4 = (const int4*)idx;
    const float2* tbl  = (const float2*)tables;

    const int gw = blockIdx.x * 4 + wave;
    const int tile0 = gw * tiles_per_wave;

    int4 iv = idx4[(tile0 * 16 + m) * 4 + q];
    float2 g0 = tbl[(q * 4 + 0) * MTBL + iv.x];
    float2 g1 = tbl[(q * 4 + 1) * MTBL + iv.y];
    float2 g2 = tbl[(q * 4 + 2) * MTBL + iv.z];
    float2 g3 = tbl[(q * 4 + 3) * MTBL + iv.w];

    for (int it = 0; it < tiles_per_wave; ++it) {
        const int pbase = (tile0 + it) * 16;
        const bool more = (it + 1) < tiles_per_wave;

        short8 Bx;
        {
            unsigned int p0 = pack2bf(g0.x, g0.y);
            unsigned int p1 = pack2bf(g1.x, g1.y);
            unsigned int p2 = pack2bf(g2.x, g2.y);
            unsigned int p3 = pack2bf(g3.x, g3.y);
            Bx[0] = (short)(p0 & 0xFFFF); Bx[1] = (short)(p0 >> 16);
            Bx[2] = (short)(p1 & 0xFFFF); Bx[3] = (short)(p1 >> 16);
            Bx[4] = (short)(p2 & 0xFFFF); Bx[5] = (short)(p2 >> 16);
            Bx[6] = (short)(p3 & 0xFFFF); Bx[7] = (short)(p3 >> 16);
        }

        int4 ivn;
        if (more) ivn = idx4[((pbase + 16) + m) * 4 + q];

        floatx4 acc[4];
#pragma unroll
        for (int t = 0; t < 4; ++t)
            acc[t] = __builtin_amdgcn_mfma_f32_16x16x32_bf16(A1[t], Bx, C1[t], 0, 0, 0);

#pragma unroll
        for (int t = 0; t < 4; ++t) {
            uint2 pk;
            pk.x = pack2bf(fmaxf(acc[t][0], 0.f), fmaxf(acc[t][1], 0.f));
            pk.y = pack2bf(fmaxf(acc[t][2], 0.f), fmaxf(acc[t][3], 0.f));
            *(uint2*)(hrow + t * 16 + q * 4) = pk;
        }
        short8 Bh0 = *(const short8*)(hrow + q * 8);
        short8 Bh1 = *(const short8*)(hrow + 32 + q * 8);

#pragma unroll
        for (int t = 0; t < 4; ++t) {
            acc[t] = __builtin_amdgcn_mfma_f32_16x16x32_bf16(A2[t][0], Bh0, C2[t], 0, 0, 0);
            acc[t] = __builtin_amdgcn_mfma_f32_16x16x32_bf16(A2[t][1], Bh1, acc[t], 0, 0, 0);
        }

        if (more) {
            g0 = tbl[(q * 4 + 0) * MTBL + ivn.x];
            g1 = tbl[(q * 4 + 1) * MTBL + ivn.y];
            g2 = tbl[(q * 4 + 2) * MTBL + ivn.z];
            g3 = tbl[(q * 4 + 3) * MTBL + ivn.w];
        }

#pragma unroll
        for (int t = 0; t < 4; ++t) {
            uint2 pk;
            pk.x = pack2bf(fmaxf(acc[t][0], 0.f), fmaxf(acc[t][1], 0.f));
            pk.y = pack2bf(fmaxf(acc[t][2], 0.f), fmaxf(acc[t][3], 0.f));
            *(uint2*)(hrow + t * 16 + q * 4) = pk;
        }
        Bh0 = *(const short8*)(hrow + q * 8);
        Bh1 = *(const short8*)(hrow + 32 + q * 8);

#pragma unroll
        for (int t = 0; t < 4; ++t) {
            acc[t] = __builtin_amdgcn_mfma_f32_16x16x32_bf16(A3[t][0], Bh0, C3[t], 0, 0, 0);
            acc[t] = __builtin_amdgcn_mfma_f32_16x16x32_bf16(A3[t][1], Bh1, acc[t], 0, 0, 0);
        }

#pragma unroll
        for (int t = 0; t < 4; ++t) {
            uint2 pk;
            pk.x = pack2bf(fmaxf(acc[t][0], 0.f), fmaxf(acc[t][1], 0.f));
            pk.y = pack2bf(fmaxf(acc[t][2], 0.f), fmaxf(acc[t][3], 0.f));
            *(uint2*)(hrow + t * 16 + q * 4) = pk;
        }
        Bh0 = *(const short8*)(hrow + q * 8);
        Bh1 = *(const short8*)(hrow + 32 + q * 8);

        floatx4 o;
        o = __builtin_amdgcn_mfma_f32_16x16x32_bf16(A4[0], Bh0, C4, 0, 0, 0);
        o = __builtin_amdgcn_mfma_f32_16x16x32_bf16(A4[1], Bh1, o, 0, 0, 0);

        if (q == 0) {
            const int pn = pbase + m;
            out[pn * 3 + 0] = o[0];
            out[pn * 3 + 1] = o[1];
            out[pn * 3 + 2] = o[2];
        }
    }
}

extern "C" void kernel_launch(void* const* d_in, const int* in_sizes, int n_in,
                              void* d_out, int out_size, void* d_ws, size_t ws_size,
                              hipStream_t stream) {
    const int*   idx    = (const int*)d_in[0];
    const float* tables = (const float*)d_in[1];
    const float* W1 = (const float*)d_in[2];
    const float* b1 = (const float*)d_in[3];
    const float* W2 = (const float*)d_in[4];
    const float* b2 = (const float*)d_in[5];
    const float* W3 = (const float*)d_in[6];
    const float* b3 = (const float*)d_in[7];
    const float* W4 = (const float*)d_in[8];
    const float* b4 = (const float*)d_in[9];
    float* out = (float*)d_out;

    const int N = in_sizes[0] / 16;            // points (2,097,152)
    const int total_tiles = N / 16;

    const size_t idxT_bytes = (size_t)16 * N * 4;           // 128 MiB
    const size_t xU_bytes   = (size_t)16 * N * 4;           // 128 MiB
    const size_t tblC_bytes = (size_t)16 * MTBL * 4;        // 32 MiB
    const size_t need = idxT_bytes + xU_bytes + tblC_bytes;

    if (ws_size >= need) {
        int*          idxT = (int*)d_ws;
        unsigned int* xU   = (unsigned int*)((char*)d_ws + idxT_bytes);
        unsigned int* tblC = (unsigned int*)((char*)d_ws + idxT_bytes + xU_bytes);

        // A: transpose idx
        ngp_transpose<<<N / 1024, 256, 0, stream>>>(idx, idxT, N);
        // T: compress tables to packed bf16 (16*M entries, 4 per thread)
        ngp_compress<<<(16 * MTBL) / 1024, 256, 0, stream>>>(
            (const floatx4*)tables, tblC);
        // B: two gather phases, one head per XCD each
        const int iters = (N >> 8) >> 11;   // points/block / 2048
        ngp_gather_ph<<<2048, 256, 0, stream>>>(idxT, tblC, xU, N, 0, iters);
        ngp_gather_ph<<<2048, 256, 0, stream>>>(idxT, tblC, xU, N, 1, iters);
        // C: MFMA MLP
        const int blocks = 2048;
        const int tiles_per_wave = total_tiles / (blocks * 4);
        ngp_mlp<<<blocks, 256, 0, stream>>>(xU, W1, b1, W2, b2, W3, b3, W4, b4,
                                            out, N, tiles_per_wave);
    } else {
        const int blocks = 2048;
        const int tiles_per_wave = total_tiles / (blocks * 4);
        ngp_fused<<<blocks, 256, 0, stream>>>(idx, tables, W1, b1, W2, b2, W3, b3,
                                              W4, b4, out, tiles_per_wave);
    }
}